// Round 1
// baseline (1570.511 us; speedup 1.0000x reference)
//
#include <hip/hip_runtime.h>
#include <cmath>

#define NN   3072
#define HIDD 256
#define TK   16
#define FEAT 768   // 3*HID

// ---------------------------------------------------------------- pool
__global__ void pool_kernel(const float* __restrict__ img, float* __restrict__ p) {
    int idx = blockIdx.x * 256 + threadIdx.x;
    if (idx >= NN * 192) return;
    int b = idx / 192, rem = idx % 192;
    int c = rem >> 6, oy = (rem >> 3) & 7, ox = rem & 7;
    const float* base = img + (((size_t)b * 3 + c) * 32 + oy * 4) * 32 + ox * 4;
    float s = 0.f;
#pragma unroll
    for (int iy = 0; iy < 4; iy++)
#pragma unroll
        for (int ix = 0; ix < 4; ix++) s += base[iy * 32 + ix];
    p[idx] = s * 0.0625f;
}

// ---------------------------------------------------------------- GEMM NN
// C[M,Nc] = act(alpha*(A@B) + bias + (acc? C : 0))
// act: 0 none, 1 relu, 2 tanh, 3 sigmoid
__global__ void gemm_nn(const float* __restrict__ A, const float* __restrict__ B,
                        const float* __restrict__ bias, float* __restrict__ C,
                        int M, int Nc, int K, int lda, int ldb, int ldc,
                        float alpha, int act, int acc) {
    __shared__ float As[16][64 + 1];
    __shared__ float Bs[16][64 + 1];
    int tid = threadIdx.x;
    int tm = tid >> 4, tn = tid & 15;
    int m0 = blockIdx.y * 64, n0 = blockIdx.x * 64;
    float accv[4][4] = {};
    for (int k0 = 0; k0 < K; k0 += 16) {
#pragma unroll
        for (int i = 0; i < 4; i++) {
            int idx = tid + i * 256;
            int kk = idx & 15, mm = idx >> 4;
            int gm = m0 + mm, gk = k0 + kk;
            As[kk][mm] = (gm < M && gk < K) ? A[(size_t)gm * lda + gk] : 0.f;
        }
#pragma unroll
        for (int i = 0; i < 4; i++) {
            int idx = tid + i * 256;
            int nn2 = idx & 63, kk = idx >> 6;
            int gk = k0 + kk, gn = n0 + nn2;
            Bs[kk][nn2] = (gk < K && gn < Nc) ? B[(size_t)gk * ldb + gn] : 0.f;
        }
        __syncthreads();
#pragma unroll
        for (int kk = 0; kk < 16; kk++) {
            float a[4], b[4];
#pragma unroll
            for (int i = 0; i < 4; i++) a[i] = As[kk][tm * 4 + i];
#pragma unroll
            for (int j = 0; j < 4; j++) b[j] = Bs[kk][tn * 4 + j];
#pragma unroll
            for (int i = 0; i < 4; i++)
#pragma unroll
                for (int j = 0; j < 4; j++) accv[i][j] += a[i] * b[j];
        }
        __syncthreads();
    }
#pragma unroll
    for (int i = 0; i < 4; i++) {
        int gm = m0 + tm * 4 + i;
        if (gm >= M) continue;
#pragma unroll
        for (int j = 0; j < 4; j++) {
            int gn = n0 + tn * 4 + j;
            if (gn >= Nc) continue;
            float v = alpha * accv[i][j];
            if (bias) v += bias[gn];
            if (acc) v += C[(size_t)gm * ldc + gn];
            if (act == 1) v = fmaxf(v, 0.f);
            else if (act == 2) v = tanhf(v);
            else if (act == 3) v = 1.f / (1.f + expf(-v));
            C[(size_t)gm * ldc + gn] = v;
        }
    }
}

// ---------------------------------------------------------------- GEMM NT (sim = Z @ Z^T)
__global__ void gemm_nt_sim(const float* __restrict__ Z, float* __restrict__ S) {
    __shared__ float As[16][64 + 1];
    __shared__ float Bs[16][64 + 1];
    int tid = threadIdx.x;
    int tm = tid >> 4, tn = tid & 15;
    int m0 = blockIdx.y * 64, n0 = blockIdx.x * 64;
    float accv[4][4] = {};
    for (int k0 = 0; k0 < HIDD; k0 += 16) {
#pragma unroll
        for (int i = 0; i < 4; i++) {
            int idx = tid + i * 256;
            int kk = idx & 15, mm = idx >> 4;
            As[kk][mm] = Z[(size_t)(m0 + mm) * HIDD + k0 + kk];
        }
#pragma unroll
        for (int i = 0; i < 4; i++) {
            int idx = tid + i * 256;
            int kk = idx & 15, mm = idx >> 4;
            Bs[kk][mm] = Z[(size_t)(n0 + mm) * HIDD + k0 + kk];
        }
        __syncthreads();
#pragma unroll
        for (int kk = 0; kk < 16; kk++) {
            float a[4], b[4];
#pragma unroll
            for (int i = 0; i < 4; i++) a[i] = As[kk][tm * 4 + i];
#pragma unroll
            for (int j = 0; j < 4; j++) b[j] = Bs[kk][tn * 4 + j];
#pragma unroll
            for (int i = 0; i < 4; i++)
#pragma unroll
                for (int j = 0; j < 4; j++) accv[i][j] += a[i] * b[j];
        }
        __syncthreads();
    }
#pragma unroll
    for (int i = 0; i < 4; i++)
#pragma unroll
        for (int j = 0; j < 4; j++)
            S[(size_t)(m0 + tm * 4 + i) * NN + n0 + tn * 4 + j] = accv[i][j];
}

// ---------------------------------------------------------------- BatchNorm (training stats), per column
__global__ void bn_kernel(float* __restrict__ Y, const float* __restrict__ g,
                          const float* __restrict__ bt) {
    int j = blockIdx.x;  // column 0..255 (Y already offset, ld = FEAT)
    __shared__ float rs[256], rs2[256];
    float s = 0.f, s2 = 0.f;
    for (int i = threadIdx.x; i < NN; i += 256) {
        float v = Y[(size_t)i * FEAT + j];
        s += v; s2 += v * v;
    }
    rs[threadIdx.x] = s; rs2[threadIdx.x] = s2;
    __syncthreads();
    for (int st = 128; st > 0; st >>= 1) {
        if (threadIdx.x < st) { rs[threadIdx.x] += rs[threadIdx.x + st]; rs2[threadIdx.x] += rs2[threadIdx.x + st]; }
        __syncthreads();
    }
    float mean = rs[0] * (1.f / NN);
    float var = fmaxf(rs2[0] * (1.f / NN) - mean * mean, 0.f);
    float scale = g[j] / sqrtf(var + 1e-5f);
    float shift = bt[j];
    for (int i = threadIdx.x; i < NN; i += 256) {
        size_t o = (size_t)i * FEAT + j;
        Y[o] = (Y[o] - mean) * scale + shift;
    }
}

// ---------------------------------------------------------------- row normalize z
__global__ void rownorm_kernel(float* __restrict__ Z) {
    int i = blockIdx.x;
    __shared__ float rs[256];
    __shared__ float inv;
    float v = Z[(size_t)i * HIDD + threadIdx.x];
    rs[threadIdx.x] = v * v;
    __syncthreads();
    for (int st = 128; st > 0; st >>= 1) {
        if (threadIdx.x < st) rs[threadIdx.x] += rs[threadIdx.x + st];
        __syncthreads();
    }
    if (threadIdx.x == 0) inv = 1.f / (sqrtf(rs[0]) + 1e-8f);
    __syncthreads();
    Z[(size_t)i * HIDD + threadIdx.x] = v * inv;
}

// ---------------------------------------------------------------- top-k per row (k=16), lower-index tie-break
__global__ void topk_kernel(const float* __restrict__ S, float* __restrict__ hv,
                            int* __restrict__ eidx) {
    int row = blockIdx.x;
    __shared__ float sv[NN];
    __shared__ float rv[256];
    __shared__ int   ri[256];
    const float* srow = S + (size_t)row * NN;
    for (int i = threadIdx.x; i < NN; i += 256) sv[i] = srow[i];
    __syncthreads();
    for (int t = 0; t < TK; t++) {
        float bv = -1e30f; int bi = NN;
        for (int i = threadIdx.x; i < NN; i += 256) {
            float v = sv[i];
            if (v > bv) { bv = v; bi = i; }
        }
        rv[threadIdx.x] = bv; ri[threadIdx.x] = bi;
        __syncthreads();
        for (int st = 128; st > 0; st >>= 1) {
            if (threadIdx.x < st) {
                float ov = rv[threadIdx.x + st]; int oi = ri[threadIdx.x + st];
                if (ov > rv[threadIdx.x] || (ov == rv[threadIdx.x] && oi < ri[threadIdx.x])) {
                    rv[threadIdx.x] = ov; ri[threadIdx.x] = oi;
                }
            }
            __syncthreads();
        }
        if (threadIdx.x == 0) {
            float val = rv[0]; int id = ri[0];
            float sg = 1.f / (1.f + expf(-val));
            hv[row * TK + t] = (sg > 0.5f) ? sg : 0.f;
            eidx[row * TK + t] = id;
            sv[id] = -1e30f;
        }
        __syncthreads();
    }
}

// ---------------------------------------------------------------- edge stats
__global__ void edge_stats(const float* __restrict__ hv, float* __restrict__ De,
                           float* __restrict__ ew) {
    int e = blockIdx.x * 256 + threadIdx.x;
    if (e >= NN) return;
    float s = 0.f;
#pragma unroll
    for (int j = 0; j < TK; j++) s += hv[e * TK + j];
    De[e] = s + 1e-8f;
    ew[e] = s * (1.f / TK);
}

__global__ void scatter_deg(const int* __restrict__ eidx, const float* __restrict__ hv,
                            const float* __restrict__ ew, float* __restrict__ Dv,
                            float* __restrict__ Dv2, int* __restrict__ row_cnt) {
    int t = blockIdx.x * 256 + threadIdx.x;
    if (t >= NN * TK) return;
    int e = t >> 4;
    int v = eidx[t];
    float w = hv[t];
    atomicAdd(&Dv[v], w * ew[e]);
    atomicAdd(&Dv2[v], w);
    atomicAdd(&row_cnt[v], 1);
}

__global__ void deg_fin(const float* __restrict__ Dv, float* __restrict__ Dv2,
                        float* __restrict__ dvis) {
    int v = blockIdx.x * 256 + threadIdx.x;
    if (v >= NN) return;
    dvis[v] = 1.f / sqrtf(Dv[v] + 1e-8f);
    Dv2[v] += 1e-8f;
}

// ---------------------------------------------------------------- CSR build
__global__ void scan_kernel(const int* __restrict__ cnt, int* __restrict__ start) {
    __shared__ int part[256];
    int t = threadIdx.x;
    const int chunk = NN / 256;  // 12
    int s = 0;
    for (int i = t * chunk; i < (t + 1) * chunk; i++) s += cnt[i];
    part[t] = s;
    __syncthreads();
    if (t == 0) {
        int a = 0;
        for (int i = 0; i < 256; i++) { int v = part[i]; part[i] = a; a += v; }
    }
    __syncthreads();
    int a = part[t];
    for (int i = t * chunk; i < (t + 1) * chunk; i++) { start[i] = a; a += cnt[i]; }
    if (t == 255) start[NN] = a;
}

__global__ void fill_csr(const int* __restrict__ eidx, const float* __restrict__ hv,
                         const int* __restrict__ start, int* __restrict__ fillc,
                         int* __restrict__ csr_e, float* __restrict__ csr_w) {
    int t = blockIdx.x * 256 + threadIdx.x;
    if (t >= NN * TK) return;
    int e = t >> 4;
    int v = eidx[t];
    int pos = atomicAdd(&fillc[v], 1);
    int pp = start[v] + pos;
    csr_e[pp] = e;
    csr_w[pp] = hv[t];
}

// ---------------------------------------------------------------- sparse H ops
// T[e,f] = (sum_j hv[e,j]*(dvis?)*X[idx[e,j],f]) / De[e]
__global__ void edge_gather(const int* __restrict__ eidx, const float* __restrict__ hv,
                            const float* __restrict__ De, const float* __restrict__ dvis,
                            const float* __restrict__ X, float* __restrict__ T,
                            int F, int use_dvis) {
    int e = blockIdx.x;
    int f = blockIdx.y * 256 + threadIdx.x;
    if (f >= F) return;
    float acc = 0.f;
#pragma unroll
    for (int j = 0; j < TK; j++) {
        int v = eidx[e * TK + j];
        float w = hv[e * TK + j];
        if (use_dvis) w *= dvis[v];
        acc += w * X[(size_t)v * F + f];
    }
    T[(size_t)e * F + f] = acc / De[e];
}

// Y[v,f] = alpha*(dvis?)*sum_{(e,w) in row v} w*T[e,f]  + beta*Badd[v,f]
__global__ void row_gather(const int* __restrict__ start, const int* __restrict__ csr_e,
                           const float* __restrict__ csr_w, const float* __restrict__ dvis,
                           const float* __restrict__ T, const float* __restrict__ Badd,
                           float alpha, float beta, float* __restrict__ Y,
                           int F, int use_dvis) {
    int v = blockIdx.x;
    int f = blockIdx.y * 256 + threadIdx.x;
    if (f >= F) return;
    int s0 = start[v], s1 = start[v + 1];
    float acc = 0.f;
    for (int p = s0; p < s1; p++) acc += csr_w[p] * T[(size_t)csr_e[p] * F + f];
    float o = alpha * (use_dvis ? dvis[v] : 1.f) * acc;
    if (Badd) o += beta * Badd[(size_t)v * F + f];
    Y[(size_t)v * F + f] = o;
}

// ---------------------------------------------------------------- reductions
__global__ void mse_reduce(const float* __restrict__ a, const float* __restrict__ b,
                           float* __restrict__ sum) {
    __shared__ float rs[256];
    float s = 0.f;
    size_t n = (size_t)NN * FEAT;
    for (size_t i = (size_t)blockIdx.x * 256 + threadIdx.x; i < n; i += (size_t)gridDim.x * 256) {
        float d = a[i] - b[i];
        s += d * d;
    }
    rs[threadIdx.x] = s;
    __syncthreads();
    for (int st = 128; st > 0; st >>= 1) {
        if (threadIdx.x < st) rs[threadIdx.x] += rs[threadIdx.x + st];
        __syncthreads();
    }
    if (threadIdx.x == 0) atomicAdd(sum, rs[0]);
}

__global__ void spectral_cols(const float* __restrict__ r, const float* __restrict__ y,
                              const float* __restrict__ Dv2, float* __restrict__ numb,
                              float* __restrict__ denb) {
    int c = blockIdx.x;  // 0..63
    __shared__ float rn[256], rd[256];
    float sn = 0.f, sd = 0.f;
    for (int i = threadIdx.x; i < NN; i += 256) {
        float rv = r[(size_t)i * 64 + c];
        float d2 = Dv2[i];
        float lcx = d2 * rv - y[(size_t)i * 64 + c];
        sn += rv * lcx;
        sd += d2 * rv * rv;
    }
    rn[threadIdx.x] = sn; rd[threadIdx.x] = sd;
    __syncthreads();
    for (int st = 128; st > 0; st >>= 1) {
        if (threadIdx.x < st) { rn[threadIdx.x] += rn[threadIdx.x + st]; rd[threadIdx.x] += rd[threadIdx.x + st]; }
        __syncthreads();
    }
    if (threadIdx.x == 0) { numb[c] = rn[0]; denb[c] = rd[0] + 1e-8f; }
}

__global__ void finals_kernel(const float* __restrict__ msum, const float* __restrict__ numb,
                              const float* __restrict__ denb, float* __restrict__ out) {
    if (threadIdx.x == 0 && blockIdx.x == 0) {
        float s = 0.f;
        for (int c = 0; c < 64; c++) s += numb[c] / denb[c];
        out[NN + 1] = s * (1.f / 64.f);
        out[NN] = msum[0] * (1.f / ((float)NN * FEAT));
    }
}

// ================================================================ launch
extern "C" void kernel_launch(void* const* d_in, const int* in_sizes, int n_in,
                              void* d_out, int out_size, void* d_ws, size_t ws_size,
                              hipStream_t stream) {
    const float* images = (const float*)d_in[0];
    const float* text   = (const float*)d_in[1];
    const float* signal = (const float*)d_in[2];
    const float* iw1 = (const float*)d_in[3];  const float* ib1 = (const float*)d_in[4];
    const float* iw2 = (const float*)d_in[5];  const float* ib2 = (const float*)d_in[6];
    const float* ig  = (const float*)d_in[7];  const float* ibeta = (const float*)d_in[8];
    const float* tw1 = (const float*)d_in[9];  const float* tb1 = (const float*)d_in[10];
    const float* tw2 = (const float*)d_in[11]; const float* tb2 = (const float*)d_in[12];
    const float* tg  = (const float*)d_in[13]; const float* tbeta = (const float*)d_in[14];
    const float* sw1 = (const float*)d_in[15]; const float* sb1 = (const float*)d_in[16];
    const float* sw2 = (const float*)d_in[17]; const float* sb2 = (const float*)d_in[18];
    const float* sg  = (const float*)d_in[19]; const float* sbeta = (const float*)d_in[20];
    const float* gw  = (const float*)d_in[21]; const float* gb = (const float*)d_in[22];
    const float* c1w = (const float*)d_in[23]; const float* c1b = (const float*)d_in[24];
    const float* c2w = (const float*)d_in[25]; const float* c2b = (const float*)d_in[26];
    const float* rw1 = (const float*)d_in[27]; const float* rb1 = (const float*)d_in[28];
    const float* rw2 = (const float*)d_in[29]; const float* rb2 = (const float*)d_in[30];
    const float* aw1 = (const float*)d_in[31]; const float* ab1 = (const float*)d_in[32];
    const float* aw2 = (const float*)d_in[33]; const float* ab2 = (const float*)d_in[34];
    const float* dw1 = (const float*)d_in[35]; const float* db1 = (const float*)d_in[36];
    const float* dw2 = (const float*)d_in[37]; const float* db2 = (const float*)d_in[38];
    float* out = (float*)d_out;

    float* wsf = (float*)d_ws;
    size_t off = 0;
    auto AF = [&](size_t n) { float* q = wsf + off; off += n; return q; };
    float* feats  = AF((size_t)NN * FEAT);
    float* simbuf = AF((size_t)NN * NN);
    float* p      = AF((size_t)NN * 192);
    float* h      = AF((size_t)NN * HIDD);
    float* z      = AF((size_t)NN * HIDD);
    float* x1     = AF((size_t)NN * HIDD);
    float* x2     = AF((size_t)NN * 128);
    float* r      = AF((size_t)NN * 64);
    float* hv     = AF((size_t)NN * TK);
    float* ew     = AF(NN);
    float* De     = AF(NN);
    float* Dv     = AF(NN);   // Dv, Dv2 contiguous -> single memset
    float* Dv2    = AF(NN);
    float* dvis   = AF(NN);
    float* csr_w  = AF((size_t)NN * TK);
    float* numb   = AF(64);
    float* denb   = AF(64);
    float* msum   = AF(1);
    int* eidx     = (int*)(wsf + off); off += (size_t)NN * TK;
    int* csr_e    = (int*)(wsf + off); off += (size_t)NN * TK;
    int* row_cnt  = (int*)(wsf + off); off += NN;   // row_cnt, row_fill contiguous
    int* row_fill = (int*)(wsf + off); off += NN;
    int* row_start= (int*)(wsf + off); off += NN + 1;

    // sim buffer recycled after top-k:
    float* T1    = simbuf;
    float* T2    = simbuf + (size_t)NN * FEAT;
    float* et    = simbuf + (size_t)2 * NN * FEAT;
    float* recon = simbuf + (size_t)3 * NN * FEAT;
    float* yspec = x2;  // x2 free after r is computed

    dim3 blk(256);
    auto gemm = [&](const float* A, const float* B, const float* bias, float* C,
                    int M, int Nc, int K, int lda, int ldb, int ldc,
                    float alpha, int act, int acc) {
        dim3 grid((Nc + 63) / 64, (M + 63) / 64);
        gemm_nn<<<grid, blk, 0, stream>>>(A, B, bias, C, M, Nc, K, lda, ldb, ldc, alpha, act, acc);
    };

    const float E1 = 0.60653065971f;  // exp(-0.5)
    const float E2 = 0.36787944117f;  // exp(-1.0)

    // ---- modality MLPs + BN ----
    pool_kernel<<<(NN * 192 + 255) / 256, blk, 0, stream>>>(images, p);
    gemm(p, iw1, ib1, h, NN, HIDD, 192, 192, HIDD, HIDD, 1.f, 1, 0);
    gemm(h, iw2, ib2, feats + 0, NN, HIDD, HIDD, HIDD, HIDD, FEAT, 1.f, 0, 0);
    bn_kernel<<<HIDD, blk, 0, stream>>>(feats + 0, ig, ibeta);

    gemm(text, tw1, tb1, h, NN, HIDD, 768, 768, HIDD, HIDD, 1.f, 1, 0);
    gemm(h, tw2, tb2, feats + HIDD, NN, HIDD, HIDD, HIDD, HIDD, FEAT, 1.f, 0, 0);
    bn_kernel<<<HIDD, blk, 0, stream>>>(feats + HIDD, tg, tbeta);

    gemm(signal, sw1, sb1, h, NN, HIDD, 256, 256, HIDD, HIDD, 1.f, 1, 0);
    gemm(h, sw2, sb2, feats + 2 * HIDD, NN, HIDD, HIDD, HIDD, HIDD, FEAT, 1.f, 0, 0);
    bn_kernel<<<HIDD, blk, 0, stream>>>(feats + 2 * HIDD, sg, sbeta);

    // ---- hyperedge generator ----
    gemm(feats, gw, gb, z, NN, HIDD, FEAT, FEAT, HIDD, HIDD, 1.f, 2, 0);
    rownorm_kernel<<<NN, blk, 0, stream>>>(z);
    gemm_nt_sim<<<dim3(NN / 64, NN / 64), blk, 0, stream>>>(z, simbuf);
    topk_kernel<<<NN, blk, 0, stream>>>(simbuf, hv, eidx);

    // ---- degrees + CSR of H rows ----
    hipMemsetAsync(Dv, 0, 2 * NN * sizeof(float), stream);
    hipMemsetAsync(msum, 0, sizeof(float), stream);
    hipMemsetAsync(row_cnt, 0, 2 * NN * sizeof(int), stream);
    edge_stats<<<NN / 256, blk, 0, stream>>>(hv, De, ew);
    scatter_deg<<<NN * TK / 256, blk, 0, stream>>>(eidx, hv, ew, Dv, Dv2, row_cnt);
    deg_fin<<<NN / 256, blk, 0, stream>>>(Dv, Dv2, dvis);
    scan_kernel<<<1, blk, 0, stream>>>(row_cnt, row_start);
    fill_csr<<<NN * TK / 256, blk, 0, stream>>>(eidx, hv, row_start, row_fill, csr_e, csr_w);

    // ---- cheb conv 1 (F=768 -> 256) ----
    edge_gather<<<dim3(NN, 3), blk, 0, stream>>>(eidx, hv, De, dvis, feats, et, FEAT, 1);
    row_gather<<<dim3(NN, 3), blk, 0, stream>>>(row_start, csr_e, csr_w, dvis, et, nullptr, -1.f, 0.f, T1, FEAT, 1);
    edge_gather<<<dim3(NN, 3), blk, 0, stream>>>(eidx, hv, De, dvis, T1, et, FEAT, 1);
    row_gather<<<dim3(NN, 3), blk, 0, stream>>>(row_start, csr_e, csr_w, dvis, et, feats, -2.f, -1.f, T2, FEAT, 1);
    gemm(feats, c1w + 0,                 nullptr, x1, NN, HIDD, FEAT, FEAT, HIDD, HIDD, 1.f, 0, 0);
    gemm(T1,    c1w + (size_t)FEAT*HIDD, nullptr, x1, NN, HIDD, FEAT, FEAT, HIDD, HIDD, E1,  0, 1);
    gemm(T2,    c1w + (size_t)2*FEAT*HIDD, c1b,   x1, NN, HIDD, FEAT, FEAT, HIDD, HIDD, E2,  1, 1);

    // ---- cheb conv 2 (F=256 -> 128) ----
    edge_gather<<<dim3(NN, 1), blk, 0, stream>>>(eidx, hv, De, dvis, x1, et, HIDD, 1);
    row_gather<<<dim3(NN, 1), blk, 0, stream>>>(row_start, csr_e, csr_w, dvis, et, nullptr, -1.f, 0.f, T1, HIDD, 1);
    edge_gather<<<dim3(NN, 1), blk, 0, stream>>>(eidx, hv, De, dvis, T1, et, HIDD, 1);
    row_gather<<<dim3(NN, 1), blk, 0, stream>>>(row_start, csr_e, csr_w, dvis, et, x1, -2.f, -1.f, T2, HIDD, 1);
    gemm(x1, c2w + 0,               nullptr, x2, NN, 128, HIDD, HIDD, 128, 128, 1.f, 0, 0);
    gemm(T1, c2w + (size_t)HIDD*128, nullptr, x2, NN, 128, HIDD, HIDD, 128, 128, E1,  0, 1);
    gemm(T2, c2w + (size_t)2*HIDD*128, c2b,   x2, NN, 128, HIDD, HIDD, 128, 128, E2,  1, 1);

    // ---- heads ----
    gemm(x2, rw1, rb1, h, NN, 64, 128, 128, 64, 64, 1.f, 1, 0);
    gemm(h,  rw2, rb2, r, NN, 64, 64, 64, 64, 64, 1.f, 0, 0);
    gemm(r,  aw1, ab1, h, NN, 32, 64, 64, 32, 32, 1.f, 1, 0);
    gemm(h,  aw2, ab2, out, NN, 1, 32, 32, 1, 1, 1.f, 3, 0);
    gemm(r,  dw1, db1, h, NN, HIDD, 64, 64, HIDD, HIDD, 1.f, 1, 0);
    gemm(h,  dw2, db2, recon, NN, FEAT, HIDD, HIDD, FEAT, FEAT, 1.f, 0, 0);
    mse_reduce<<<512, blk, 0, stream>>>(recon, feats, msum);

    // ---- spectral cut ----
    edge_gather<<<dim3(NN, 1), blk, 0, stream>>>(eidx, hv, De, dvis, r, et, 64, 0);
    row_gather<<<dim3(NN, 1), blk, 0, stream>>>(row_start, csr_e, csr_w, dvis, et, nullptr, 1.f, 0.f, yspec, 64, 0);
    spectral_cols<<<64, blk, 0, stream>>>(r, yspec, Dv2, numb, denb);
    finals_kernel<<<1, 64, 0, stream>>>(msum, numb, denb, out);
}

// Round 2
// 774.164 us; speedup vs baseline: 2.0287x; 2.0287x over previous
//
#include <hip/hip_runtime.h>
#include <cmath>

#define NN   3072
#define HIDD 256
#define TK   16
#define FEAT 768   // 3*HID

// ---------------------------------------------------------------- pool
__global__ void pool_kernel(const float* __restrict__ img, float* __restrict__ p) {
    int idx = blockIdx.x * 256 + threadIdx.x;
    if (idx >= NN * 192) return;
    int b = idx / 192, rem = idx % 192;
    int c = rem >> 6, oy = (rem >> 3) & 7, ox = rem & 7;
    const float* base = img + (((size_t)b * 3 + c) * 32 + oy * 4) * 32 + ox * 4;
    float s = 0.f;
#pragma unroll
    for (int iy = 0; iy < 4; iy++)
#pragma unroll
        for (int ix = 0; ix < 4; ix++) s += base[iy * 32 + ix];
    p[idx] = s * 0.0625f;
}

// ---------------------------------------------------------------- GEMM (split-K partials)
// P[s][M][Nc] += A[m0..][kchunk] @ B[kchunk][n0..]   (plain stores; epilogue reduces)
__global__ void gemm2(const float* __restrict__ A, const float* __restrict__ B,
                      float* __restrict__ P, int M, int Nc, int K,
                      int lda, int ldb, int Kc) {
    __shared__ float As[32][68];
    __shared__ float Bs[32][68];
    int tid = threadIdx.x;
    int tm = tid >> 4, tn = tid & 15;
    int m0 = blockIdx.y * 64, n0 = blockIdx.x * 64;
    int kbeg = blockIdx.z * Kc;
    int kend = min(K, kbeg + Kc);
    float acc[4][4] = {};
    for (int k0 = kbeg; k0 < kend; k0 += 32) {
        // A tile: 64 rows x 32 k -> store K-major (transposed)
#pragma unroll
        for (int i = 0; i < 2; i++) {
            int q = tid + i * 256;
            int m = q >> 3, kq = q & 7;
            float4 v = *(const float4*)(A + (size_t)(m0 + m) * lda + k0 + kq * 4);
            As[kq * 4 + 0][m] = v.x;
            As[kq * 4 + 1][m] = v.y;
            As[kq * 4 + 2][m] = v.z;
            As[kq * 4 + 3][m] = v.w;
        }
        // B tile: 32 k x 64 n (already K-major)
#pragma unroll
        for (int i = 0; i < 2; i++) {
            int q = tid + i * 256;
            int k = q >> 4, nq = q & 15;
            int gn = n0 + nq * 4;
            float4 v;
            const float* src = B + (size_t)(k0 + k) * ldb + gn;
            if (gn + 3 < Nc) {
                v = *(const float4*)src;
            } else {
                v.x = (gn + 0 < Nc) ? src[0] : 0.f;
                v.y = (gn + 1 < Nc) ? src[1] : 0.f;
                v.z = (gn + 2 < Nc) ? src[2] : 0.f;
                v.w = (gn + 3 < Nc) ? src[3] : 0.f;
            }
            *(float4*)&Bs[k][nq * 4] = v;
        }
        __syncthreads();
#pragma unroll
        for (int kk = 0; kk < 32; kk++) {
            float4 a = *(const float4*)&As[kk][tm * 4];
            float4 b = *(const float4*)&Bs[kk][tn * 4];
            acc[0][0] += a.x * b.x; acc[0][1] += a.x * b.y; acc[0][2] += a.x * b.z; acc[0][3] += a.x * b.w;
            acc[1][0] += a.y * b.x; acc[1][1] += a.y * b.y; acc[1][2] += a.y * b.z; acc[1][3] += a.y * b.w;
            acc[2][0] += a.z * b.x; acc[2][1] += a.z * b.y; acc[2][2] += a.z * b.z; acc[2][3] += a.z * b.w;
            acc[3][0] += a.w * b.x; acc[3][1] += a.w * b.y; acc[3][2] += a.w * b.z; acc[3][3] += a.w * b.w;
        }
        __syncthreads();
    }
    float* Pp = P + (size_t)blockIdx.z * M * Nc;
    int gn = n0 + tn * 4;
#pragma unroll
    for (int i = 0; i < 4; i++) {
        int gm = m0 + tm * 4 + i;
        if (gn + 3 < Nc) {
            float4 v; v.x = acc[i][0]; v.y = acc[i][1]; v.z = acc[i][2]; v.w = acc[i][3];
            *(float4*)&Pp[(size_t)gm * Nc + gn] = v;
        } else {
#pragma unroll
            for (int j = 0; j < 4; j++)
                if (gn + j < Nc) Pp[(size_t)gm * Nc + gn + j] = acc[i][j];
        }
    }
}

// epilogue: C = act(alpha*sum_s P[s] + bias + acc*C)
__global__ void gemm_epi(const float* __restrict__ P, const float* __restrict__ bias,
                         float* __restrict__ C, int M, int Nc, int ldc, int KS,
                         float alpha, int act, int acc) {
    int idx = blockIdx.x * 256 + threadIdx.x;
    if (idx >= M * Nc) return;
    int m = idx / Nc, n = idx - m * Nc;
    float v = 0.f;
    for (int s = 0; s < KS; s++) v += P[(size_t)s * M * Nc + idx];
    v *= alpha;
    if (bias) v += bias[n];
    if (acc) v += C[(size_t)m * ldc + n];
    if (act == 1) v = fmaxf(v, 0.f);
    else if (act == 2) v = tanhf(v);
    else if (act == 3) v = 1.f / (1.f + expf(-v));
    C[(size_t)m * ldc + n] = v;
}

// ---------------------------------------------------------------- sim = Z @ Z^T (K=256)
__global__ void gemm_nt_sim2(const float* __restrict__ Z, float* __restrict__ S) {
    __shared__ float As[32][68];
    __shared__ float Bs[32][68];
    int tid = threadIdx.x;
    int tm = tid >> 4, tn = tid & 15;
    int m0 = blockIdx.y * 64, n0 = blockIdx.x * 64;
    float acc[4][4] = {};
    for (int k0 = 0; k0 < HIDD; k0 += 32) {
#pragma unroll
        for (int i = 0; i < 2; i++) {
            int q = tid + i * 256;
            int m = q >> 3, kq = q & 7;
            float4 v = *(const float4*)(Z + (size_t)(m0 + m) * HIDD + k0 + kq * 4);
            As[kq * 4 + 0][m] = v.x; As[kq * 4 + 1][m] = v.y;
            As[kq * 4 + 2][m] = v.z; As[kq * 4 + 3][m] = v.w;
        }
#pragma unroll
        for (int i = 0; i < 2; i++) {
            int q = tid + i * 256;
            int m = q >> 3, kq = q & 7;
            float4 v = *(const float4*)(Z + (size_t)(n0 + m) * HIDD + k0 + kq * 4);
            Bs[kq * 4 + 0][m] = v.x; Bs[kq * 4 + 1][m] = v.y;
            Bs[kq * 4 + 2][m] = v.z; Bs[kq * 4 + 3][m] = v.w;
        }
        __syncthreads();
#pragma unroll
        for (int kk = 0; kk < 32; kk++) {
            float4 a = *(const float4*)&As[kk][tm * 4];
            float4 b = *(const float4*)&Bs[kk][tn * 4];
            acc[0][0] += a.x * b.x; acc[0][1] += a.x * b.y; acc[0][2] += a.x * b.z; acc[0][3] += a.x * b.w;
            acc[1][0] += a.y * b.x; acc[1][1] += a.y * b.y; acc[1][2] += a.y * b.z; acc[1][3] += a.y * b.w;
            acc[2][0] += a.z * b.x; acc[2][1] += a.z * b.y; acc[2][2] += a.z * b.z; acc[2][3] += a.z * b.w;
            acc[3][0] += a.w * b.x; acc[3][1] += a.w * b.y; acc[3][2] += a.w * b.z; acc[3][3] += a.w * b.w;
        }
        __syncthreads();
    }
#pragma unroll
    for (int i = 0; i < 4; i++) {
        float4 v; v.x = acc[i][0]; v.y = acc[i][1]; v.z = acc[i][2]; v.w = acc[i][3];
        *(float4*)&S[(size_t)(m0 + tm * 4 + i) * NN + n0 + tn * 4] = v;
    }
}

// ---------------------------------------------------------------- BatchNorm (training stats), per column
__global__ void bn_kernel(float* __restrict__ Y, const float* __restrict__ g,
                          const float* __restrict__ bt) {
    int j = blockIdx.x;
    __shared__ float rs[256], rs2[256];
    float s = 0.f, s2 = 0.f;
    for (int i = threadIdx.x; i < NN; i += 256) {
        float v = Y[(size_t)i * FEAT + j];
        s += v; s2 += v * v;
    }
    rs[threadIdx.x] = s; rs2[threadIdx.x] = s2;
    __syncthreads();
    for (int st = 128; st > 0; st >>= 1) {
        if (threadIdx.x < st) { rs[threadIdx.x] += rs[threadIdx.x + st]; rs2[threadIdx.x] += rs2[threadIdx.x + st]; }
        __syncthreads();
    }
    float mean = rs[0] * (1.f / NN);
    float var = fmaxf(rs2[0] * (1.f / NN) - mean * mean, 0.f);
    float scale = g[j] / sqrtf(var + 1e-5f);
    float shift = bt[j];
    for (int i = threadIdx.x; i < NN; i += 256) {
        size_t o = (size_t)i * FEAT + j;
        Y[o] = (Y[o] - mean) * scale + shift;
    }
}

// ---------------------------------------------------------------- row normalize z
__global__ void rownorm_kernel(float* __restrict__ Z) {
    int i = blockIdx.x;
    __shared__ float rs[256];
    __shared__ float inv;
    float v = Z[(size_t)i * HIDD + threadIdx.x];
    rs[threadIdx.x] = v * v;
    __syncthreads();
    for (int st = 128; st > 0; st >>= 1) {
        if (threadIdx.x < st) rs[threadIdx.x] += rs[threadIdx.x + st];
        __syncthreads();
    }
    if (threadIdx.x == 0) inv = 1.f / (sqrtf(rs[0]) + 1e-8f);
    __syncthreads();
    Z[(size_t)i * HIDD + threadIdx.x] = v * inv;
}

// ---------------------------------------------------------------- top-k per row (k=16)
__global__ void topk_kernel(const float* __restrict__ S, float* __restrict__ hv,
                            int* __restrict__ eidx) {
    int row = blockIdx.x;
    __shared__ float sv[NN];
    __shared__ float rv[256];
    __shared__ int   ri[256];
    const float* srow = S + (size_t)row * NN;
    for (int i = threadIdx.x; i < NN; i += 256) sv[i] = srow[i];
    __syncthreads();
    for (int t = 0; t < TK; t++) {
        float bv = -1e30f; int bi = NN;
        for (int i = threadIdx.x; i < NN; i += 256) {
            float v = sv[i];
            if (v > bv) { bv = v; bi = i; }
        }
        rv[threadIdx.x] = bv; ri[threadIdx.x] = bi;
        __syncthreads();
        for (int st = 128; st > 0; st >>= 1) {
            if (threadIdx.x < st) {
                float ov = rv[threadIdx.x + st]; int oi = ri[threadIdx.x + st];
                if (ov > rv[threadIdx.x] || (ov == rv[threadIdx.x] && oi < ri[threadIdx.x])) {
                    rv[threadIdx.x] = ov; ri[threadIdx.x] = oi;
                }
            }
            __syncthreads();
        }
        if (threadIdx.x == 0) {
            float val = rv[0]; int id = ri[0];
            float sg = 1.f / (1.f + expf(-val));
            hv[row * TK + t] = (sg > 0.5f) ? sg : 0.f;
            eidx[row * TK + t] = id;
            sv[id] = -1e30f;
        }
        __syncthreads();
    }
}

// ---------------------------------------------------------------- edge stats
__global__ void edge_stats(const float* __restrict__ hv, float* __restrict__ De,
                           float* __restrict__ ew) {
    int e = blockIdx.x * 256 + threadIdx.x;
    if (e >= NN) return;
    float s = 0.f;
#pragma unroll
    for (int j = 0; j < TK; j++) s += hv[e * TK + j];
    De[e] = s + 1e-8f;
    ew[e] = s * (1.f / TK);
}

__global__ void scatter_deg(const int* __restrict__ eidx, const float* __restrict__ hv,
                            const float* __restrict__ ew, float* __restrict__ Dv,
                            float* __restrict__ Dv2, int* __restrict__ row_cnt) {
    int t = blockIdx.x * 256 + threadIdx.x;
    if (t >= NN * TK) return;
    int e = t >> 4;
    int v = eidx[t];
    float w = hv[t];
    atomicAdd(&Dv[v], w * ew[e]);
    atomicAdd(&Dv2[v], w);
    atomicAdd(&row_cnt[v], 1);
}

__global__ void deg_fin(const float* __restrict__ Dv, float* __restrict__ Dv2,
                        float* __restrict__ dvis) {
    int v = blockIdx.x * 256 + threadIdx.x;
    if (v >= NN) return;
    dvis[v] = 1.f / sqrtf(Dv[v] + 1e-8f);
    Dv2[v] += 1e-8f;
}

// ---------------------------------------------------------------- CSR build
__global__ void scan_kernel(const int* __restrict__ cnt, int* __restrict__ start) {
    __shared__ int part[256];
    int t = threadIdx.x;
    const int chunk = NN / 256;
    int s = 0;
    for (int i = t * chunk; i < (t + 1) * chunk; i++) s += cnt[i];
    part[t] = s;
    __syncthreads();
    if (t == 0) {
        int a = 0;
        for (int i = 0; i < 256; i++) { int v = part[i]; part[i] = a; a += v; }
    }
    __syncthreads();
    int a = part[t];
    for (int i = t * chunk; i < (t + 1) * chunk; i++) { start[i] = a; a += cnt[i]; }
    if (t == 255) start[NN] = a;
}

__global__ void fill_csr(const int* __restrict__ eidx, const float* __restrict__ hv,
                         const int* __restrict__ start, int* __restrict__ fillc,
                         int* __restrict__ csr_e, float* __restrict__ csr_w) {
    int t = blockIdx.x * 256 + threadIdx.x;
    if (t >= NN * TK) return;
    int e = t >> 4;
    int v = eidx[t];
    int pos = atomicAdd(&fillc[v], 1);
    int pp = start[v] + pos;
    csr_e[pp] = e;
    csr_w[pp] = hv[t];
}

// ---------------------------------------------------------------- sparse H ops
__global__ void edge_gather(const int* __restrict__ eidx, const float* __restrict__ hv,
                            const float* __restrict__ De, const float* __restrict__ dvis,
                            const float* __restrict__ X, float* __restrict__ T,
                            int F, int use_dvis) {
    int e = blockIdx.x;
    int f = blockIdx.y * 256 + threadIdx.x;
    if (f >= F) return;
    float acc = 0.f;
#pragma unroll
    for (int j = 0; j < TK; j++) {
        int v = eidx[e * TK + j];
        float w = hv[e * TK + j];
        if (use_dvis) w *= dvis[v];
        acc += w * X[(size_t)v * F + f];
    }
    T[(size_t)e * F + f] = acc / De[e];
}

__global__ void row_gather(const int* __restrict__ start, const int* __restrict__ csr_e,
                           const float* __restrict__ csr_w, const float* __restrict__ dvis,
                           const float* __restrict__ T, const float* __restrict__ Badd,
                           float alpha, float beta, float* __restrict__ Y,
                           int F, int use_dvis) {
    int v = blockIdx.x;
    int f = blockIdx.y * 256 + threadIdx.x;
    if (f >= F) return;
    int s0 = start[v], s1 = start[v + 1];
    float acc = 0.f;
    for (int p = s0; p < s1; p++) acc += csr_w[p] * T[(size_t)csr_e[p] * F + f];
    float o = alpha * (use_dvis ? dvis[v] : 1.f) * acc;
    if (Badd) o += beta * Badd[(size_t)v * F + f];
    Y[(size_t)v * F + f] = o;
}

// ---------------------------------------------------------------- reductions
__global__ void mse_reduce(const float* __restrict__ a, const float* __restrict__ b,
                           float* __restrict__ sum) {
    __shared__ float rs[256];
    float s = 0.f;
    size_t n = (size_t)NN * FEAT;
    for (size_t i = (size_t)blockIdx.x * 256 + threadIdx.x; i < n; i += (size_t)gridDim.x * 256) {
        float d = a[i] - b[i];
        s += d * d;
    }
    rs[threadIdx.x] = s;
    __syncthreads();
    for (int st = 128; st > 0; st >>= 1) {
        if (threadIdx.x < st) rs[threadIdx.x] += rs[threadIdx.x + st];
        __syncthreads();
    }
    if (threadIdx.x == 0) atomicAdd(sum, rs[0]);
}

__global__ void spectral_cols(const float* __restrict__ r, const float* __restrict__ y,
                              const float* __restrict__ Dv2, float* __restrict__ numb,
                              float* __restrict__ denb) {
    int c = blockIdx.x;
    __shared__ float rn[256], rd[256];
    float sn = 0.f, sd = 0.f;
    for (int i = threadIdx.x; i < NN; i += 256) {
        float rv = r[(size_t)i * 64 + c];
        float d2 = Dv2[i];
        float lcx = d2 * rv - y[(size_t)i * 64 + c];
        sn += rv * lcx;
        sd += d2 * rv * rv;
    }
    rn[threadIdx.x] = sn; rd[threadIdx.x] = sd;
    __syncthreads();
    for (int st = 128; st > 0; st >>= 1) {
        if (threadIdx.x < st) { rn[threadIdx.x] += rn[threadIdx.x + st]; rd[threadIdx.x] += rd[threadIdx.x + st]; }
        __syncthreads();
    }
    if (threadIdx.x == 0) { numb[c] = rn[0]; denb[c] = rd[0] + 1e-8f; }
}

__global__ void finals_kernel(const float* __restrict__ msum, const float* __restrict__ numb,
                              const float* __restrict__ denb, float* __restrict__ out) {
    if (threadIdx.x == 0 && blockIdx.x == 0) {
        float s = 0.f;
        for (int c = 0; c < 64; c++) s += numb[c] / denb[c];
        out[NN + 1] = s * (1.f / 64.f);
        out[NN] = msum[0] * (1.f / ((float)NN * FEAT));
    }
}

// ================================================================ launch
extern "C" void kernel_launch(void* const* d_in, const int* in_sizes, int n_in,
                              void* d_out, int out_size, void* d_ws, size_t ws_size,
                              hipStream_t stream) {
    const float* images = (const float*)d_in[0];
    const float* text   = (const float*)d_in[1];
    const float* signal = (const float*)d_in[2];
    const float* iw1 = (const float*)d_in[3];  const float* ib1 = (const float*)d_in[4];
    const float* iw2 = (const float*)d_in[5];  const float* ib2 = (const float*)d_in[6];
    const float* ig  = (const float*)d_in[7];  const float* ibeta = (const float*)d_in[8];
    const float* tw1 = (const float*)d_in[9];  const float* tb1 = (const float*)d_in[10];
    const float* tw2 = (const float*)d_in[11]; const float* tb2 = (const float*)d_in[12];
    const float* tg  = (const float*)d_in[13]; const float* tbeta = (const float*)d_in[14];
    const float* sw1 = (const float*)d_in[15]; const float* sb1 = (const float*)d_in[16];
    const float* sw2 = (const float*)d_in[17]; const float* sb2 = (const float*)d_in[18];
    const float* sg  = (const float*)d_in[19]; const float* sbeta = (const float*)d_in[20];
    const float* gw  = (const float*)d_in[21]; const float* gb = (const float*)d_in[22];
    const float* c1w = (const float*)d_in[23]; const float* c1b = (const float*)d_in[24];
    const float* c2w = (const float*)d_in[25]; const float* c2b = (const float*)d_in[26];
    const float* rw1 = (const float*)d_in[27]; const float* rb1 = (const float*)d_in[28];
    const float* rw2 = (const float*)d_in[29]; const float* rb2 = (const float*)d_in[30];
    const float* aw1 = (const float*)d_in[31]; const float* ab1 = (const float*)d_in[32];
    const float* aw2 = (const float*)d_in[33]; const float* ab2 = (const float*)d_in[34];
    const float* dw1 = (const float*)d_in[35]; const float* db1 = (const float*)d_in[36];
    const float* dw2 = (const float*)d_in[37]; const float* db2 = (const float*)d_in[38];
    float* out = (float*)d_out;

    float* wsf = (float*)d_ws;
    size_t off = 0;
    auto AF = [&](size_t n) { float* q = wsf + off; off += n; return q; };
    float* feats  = AF((size_t)NN * FEAT);
    float* simbuf = AF((size_t)NN * NN);
    float* p      = AF((size_t)NN * 192);
    float* h      = AF((size_t)NN * HIDD);
    float* z      = AF((size_t)NN * HIDD);
    float* x1     = AF((size_t)NN * HIDD);
    float* x2     = AF((size_t)NN * 128);
    float* r      = AF((size_t)NN * 64);
    float* hv     = AF((size_t)NN * TK);
    float* ew     = AF(NN);
    float* De     = AF(NN);
    float* Dv     = AF(NN);
    float* Dv2    = AF(NN);
    float* dvis   = AF(NN);
    float* csr_w  = AF((size_t)NN * TK);
    float* numb   = AF(64);
    float* denb   = AF(64);
    float* msum   = AF(1);
    int* eidx     = (int*)(wsf + off); off += (size_t)NN * TK;
    int* csr_e    = (int*)(wsf + off); off += (size_t)NN * TK;
    int* row_cnt  = (int*)(wsf + off); off += NN;
    int* row_fill = (int*)(wsf + off); off += NN;
    int* row_start= (int*)(wsf + off); off += NN + 1;

    // sim buffer recycled after top-k:
    float* T1    = simbuf;
    float* T2    = simbuf + (size_t)NN * FEAT;
    float* et    = simbuf + (size_t)2 * NN * FEAT;
    float* recon = simbuf + (size_t)3 * NN * FEAT;  // also = partial buffer for cheb/head GEMMs
    float* yspec = x2;

    dim3 blk(256);
    auto gemm = [&](const float* A, const float* B, const float* bias, float* C,
                    int M, int Nc, int K, int lda, int ldb, int ldc,
                    float alpha, int act, int acc, int KS, float* part) {
        int nk = K / 32;                      // all K are multiples of 32
        int ks = KS < nk ? KS : nk;
        int kc = ((nk + ks - 1) / ks) * 32;   // chunk (multiple of 32)
        int ksp = (K + kc - 1) / kc;          // actual splits
        gemm2<<<dim3((Nc + 63) / 64, M / 64, ksp), blk, 0, stream>>>(A, B, part, M, Nc, K, lda, ldb, kc);
        gemm_epi<<<((size_t)M * Nc + 255) / 256, blk, 0, stream>>>(part, bias, C, M, Nc, ldc, ksp, alpha, act, acc);
    };

    const float E1 = 0.60653065971f;  // exp(-0.5)
    const float E2 = 0.36787944117f;  // exp(-1.0)

    // ---- modality MLPs + BN (partials live in simbuf: free until sim) ----
    pool_kernel<<<(NN * 192 + 255) / 256, blk, 0, stream>>>(images, p);
    gemm(p, iw1, ib1, h, NN, HIDD, 192, 192, HIDD, HIDD, 1.f, 1, 0, 4, simbuf);
    gemm(h, iw2, ib2, feats + 0, NN, HIDD, HIDD, HIDD, HIDD, FEAT, 1.f, 0, 0, 4, simbuf);
    bn_kernel<<<HIDD, blk, 0, stream>>>(feats + 0, ig, ibeta);

    gemm(text, tw1, tb1, h, NN, HIDD, 768, 768, HIDD, HIDD, 1.f, 1, 0, 4, simbuf);
    gemm(h, tw2, tb2, feats + HIDD, NN, HIDD, HIDD, HIDD, HIDD, FEAT, 1.f, 0, 0, 4, simbuf);
    bn_kernel<<<HIDD, blk, 0, stream>>>(feats + HIDD, tg, tbeta);

    gemm(signal, sw1, sb1, h, NN, HIDD, 256, 256, HIDD, HIDD, 1.f, 1, 0, 4, simbuf);
    gemm(h, sw2, sb2, feats + 2 * HIDD, NN, HIDD, HIDD, HIDD, HIDD, FEAT, 1.f, 0, 0, 4, simbuf);
    bn_kernel<<<HIDD, blk, 0, stream>>>(feats + 2 * HIDD, sg, sbeta);

    // ---- hyperedge generator ----
    gemm(feats, gw, gb, z, NN, HIDD, FEAT, FEAT, HIDD, HIDD, 1.f, 2, 0, 4, simbuf);
    rownorm_kernel<<<NN, blk, 0, stream>>>(z);
    gemm_nt_sim2<<<dim3(NN / 64, NN / 64), blk, 0, stream>>>(z, simbuf);
    topk_kernel<<<NN, blk, 0, stream>>>(simbuf, hv, eidx);

    // ---- degrees + CSR of H rows ----
    hipMemsetAsync(Dv, 0, 2 * NN * sizeof(float), stream);
    hipMemsetAsync(msum, 0, sizeof(float), stream);
    hipMemsetAsync(row_cnt, 0, 2 * NN * sizeof(int), stream);
    edge_stats<<<NN / 256, blk, 0, stream>>>(hv, De, ew);
    scatter_deg<<<NN * TK / 256, blk, 0, stream>>>(eidx, hv, ew, Dv, Dv2, row_cnt);
    deg_fin<<<NN / 256, blk, 0, stream>>>(Dv, Dv2, dvis);
    scan_kernel<<<1, blk, 0, stream>>>(row_cnt, row_start);
    fill_csr<<<NN * TK / 256, blk, 0, stream>>>(eidx, hv, row_start, row_fill, csr_e, csr_w);

    // ---- cheb conv 1 (F=768 -> 256); partials in recon region (9.4MB, KS=3 fits exactly) ----
    edge_gather<<<dim3(NN, 3), blk, 0, stream>>>(eidx, hv, De, dvis, feats, et, FEAT, 1);
    row_gather<<<dim3(NN, 3), blk, 0, stream>>>(row_start, csr_e, csr_w, dvis, et, nullptr, -1.f, 0.f, T1, FEAT, 1);
    edge_gather<<<dim3(NN, 3), blk, 0, stream>>>(eidx, hv, De, dvis, T1, et, FEAT, 1);
    row_gather<<<dim3(NN, 3), blk, 0, stream>>>(row_start, csr_e, csr_w, dvis, et, feats, -2.f, -1.f, T2, FEAT, 1);
    gemm(feats, c1w + 0,                   nullptr, x1, NN, HIDD, FEAT, FEAT, HIDD, HIDD, 1.f, 0, 0, 3, recon);
    gemm(T1,    c1w + (size_t)FEAT*HIDD,   nullptr, x1, NN, HIDD, FEAT, FEAT, HIDD, HIDD, E1,  0, 1, 3, recon);
    gemm(T2,    c1w + (size_t)2*FEAT*HIDD, c1b,     x1, NN, HIDD, FEAT, FEAT, HIDD, HIDD, E2,  1, 1, 3, recon);

    // ---- cheb conv 2 (F=256 -> 128) ----
    edge_gather<<<dim3(NN, 1), blk, 0, stream>>>(eidx, hv, De, dvis, x1, et, HIDD, 1);
    row_gather<<<dim3(NN, 1), blk, 0, stream>>>(row_start, csr_e, csr_w, dvis, et, nullptr, -1.f, 0.f, T1, HIDD, 1);
    edge_gather<<<dim3(NN, 1), blk, 0, stream>>>(eidx, hv, De, dvis, T1, et, HIDD, 1);
    row_gather<<<dim3(NN, 1), blk, 0, stream>>>(row_start, csr_e, csr_w, dvis, et, x1, -2.f, -1.f, T2, HIDD, 1);
    gemm(x1, c2w + 0,                nullptr, x2, NN, 128, HIDD, HIDD, 128, 128, 1.f, 0, 0, 4, recon);
    gemm(T1, c2w + (size_t)HIDD*128, nullptr, x2, NN, 128, HIDD, HIDD, 128, 128, E1,  0, 1, 4, recon);
    gemm(T2, c2w + (size_t)2*HIDD*128, c2b,   x2, NN, 128, HIDD, HIDD, 128, 128, E2,  1, 1, 4, recon);

    // ---- heads ----
    gemm(x2, rw1, rb1, h, NN, 64, 128, 128, 64, 64, 1.f, 1, 0, 4, recon);
    gemm(h,  rw2, rb2, r, NN, 64, 64, 64, 64, 64, 1.f, 0, 0, 2, recon);
    gemm(r,  aw1, ab1, h, NN, 32, 64, 64, 32, 32, 1.f, 1, 0, 2, recon);
    gemm(h,  aw2, ab2, out, NN, 1, 32, 32, 1, 1, 1.f, 3, 0, 1, recon);
    gemm(r,  dw1, db1, h, NN, HIDD, 64, 64, HIDD, HIDD, 1.f, 1, 0, 2, recon);
    // dw2: partial (KS=1, 9.4MB) in T1 region (free after cheb2); epilogue writes recon
    gemm(h,  dw2, db2, recon, NN, FEAT, HIDD, HIDD, FEAT, FEAT, 1.f, 0, 0, 1, T1);
    mse_reduce<<<512, blk, 0, stream>>>(recon, feats, msum);

    // ---- spectral cut ----
    edge_gather<<<dim3(NN, 1), blk, 0, stream>>>(eidx, hv, De, dvis, r, et, 64, 0);
    row_gather<<<dim3(NN, 1), blk, 0, stream>>>(row_start, csr_e, csr_w, dvis, et, nullptr, 1.f, 0.f, yspec, 64, 0);
    spectral_cols<<<64, blk, 0, stream>>>(r, yspec, Dv2, numb, denb);
    finals_kernel<<<1, 64, 0, stream>>>(msum, numb, denb, out);
}